// Round 9
// baseline (28215.143 us; speedup 1.0000x reference)
//
#include <hip/hip_runtime.h>
#include <cstdint>

#define T_STEPS 8192
#define HDIM    1024
#define NBLK    256
#define NTHR    256

typedef float        f32x4 __attribute__((ext_vector_type(4)));
typedef unsigned int u32x4 __attribute__((ext_vector_type(4)));

__device__ __forceinline__ float dot4(f32x4 a, f32x4 b) {
    return a[0] * b[0] + a[1] * b[1] + a[2] * b[2] + a[3] * b[3];
}
__device__ __forceinline__ float sigmoidf_(float v) { return 1.0f / (1.0f + __expf(-v)); }
__device__ __forceinline__ float tanhf_(float v)    { return 1.0f - 2.0f / (__expf(2.0f * v) + 1.0f); }
__device__ __forceinline__ unsigned bf16_rne(float f) {
    unsigned b = __float_as_uint(f);
    return (b + 0x7FFFu + ((b >> 16) & 1u)) >> 16;
}

// ======== phase 1: gxT[bg][t][q*4+r] = x[t]·W_ih[1024q+4bg+r] + bias ========
// (verbatim R4 — correctness-proven, absmax 2e-3)
__global__ __launch_bounds__(256)
void gemm_gx(const float* __restrict__ x, const float* __restrict__ W_ih,
             const float* __restrict__ b_ih, const float* __restrict__ b_hh,
             float* __restrict__ gxT)
{
    __shared__ float a_s[16][68];
    __shared__ float b_s[16][68];
    const int t  = threadIdx.x;
    const int bm = blockIdx.x >> 6;
    const int bn = blockIdx.x & 63;
    const int m0 = bm << 6, n0 = bn << 6;
    const int tx = t & 15, ty = t >> 4;
    const int lm = t >> 2;
    const int lk = (t & 3) << 2;

    float acc[4][4] = {};
    for (int k0 = 0; k0 < 1024; k0 += 16) {
        f32x4 av = *(const f32x4*)(x    + (size_t)(m0 + lm) * 1024 + k0 + lk);
        f32x4 bv = *(const f32x4*)(W_ih + (size_t)(n0 + lm) * 1024 + k0 + lk);
        __syncthreads();
#pragma unroll
        for (int j = 0; j < 4; ++j) { a_s[lk + j][lm] = av[j]; b_s[lk + j][lm] = bv[j]; }
        __syncthreads();
#pragma unroll
        for (int k = 0; k < 16; ++k) {
            f32x4 af = *(const f32x4*)&a_s[k][4 * ty];
            f32x4 bf = *(const f32x4*)&b_s[k][4 * tx];
#pragma unroll
            for (int i = 0; i < 4; ++i)
#pragma unroll
                for (int j = 0; j < 4; ++j) acc[i][j] += af[i] * bf[j];
        }
    }
    f32x4 bi = *(const f32x4*)&b_ih[n0 + 4 * tx];
    f32x4 bh = *(const f32x4*)&b_hh[n0 + 4 * tx];
#pragma unroll
    for (int j = 0; j < 4; ++j) {
        const int n = n0 + 4 * tx + j;
        const float bias = bi[j] + bh[j];
        const int q = n >> 10, cidx = n & 1023;
        const int bg = cidx >> 2, r = cidx & 3;
#pragma unroll
        for (int i = 0; i < 4; ++i) {
            const int m = m0 + 4 * ty + i;
            gxT[((size_t)bg * T_STEPS + m) * 16 + q * 4 + r] = acc[i][j] + bias;
        }
    }
}

// ======== phase 2: R8's ring + lean loop (whh in regs, gx precomputed) ========
// 256 blocks x 256 threads. Wave w owns unit u = 4b+w. Loop register diet:
// whh 64 VGPR + ~40 overhead = the ~104 the allocator actually grants
// (R1/R3/R8 all converged there). No wih, no x — per-step global reads are
// one 64B gx line (L3, prefetch dist 2). Ring: u32[2][NBLK][16], ONE writer
// CU per 64B line (R8's proven layout; R7 showed shared-line writers cost
// +50%). Payload (epoch16<<16)|bf16(h) — bf16 handoff validated in R7/R8.
__global__ __launch_bounds__(NTHR, 1)
void lstm_loop(const float* __restrict__ W_hh,
               const float* __restrict__ h0,
               const float* __restrict__ c0,
               const float* __restrict__ gxT,
               float* __restrict__ out,
               unsigned int* __restrict__ ring)
{
    __shared__ float h_lds[2][HDIM];

    const int tid = threadIdx.x;
    const int w   = tid >> 6;   // wave 0..3
    const int l   = tid & 63;   // lane
    const int u   = (blockIdx.x << 2) + w;

    // ---- whh: lane l covers elements 4l + 256i; 64 VGPRs, loop-resident ----
    f32x4 whh[16];
#pragma unroll
    for (int q = 0; q < 4; ++q) {
        const float* rh = W_hh + (size_t)(q * HDIM + u) * HDIM + 4 * l;
#pragma unroll
        for (int i = 0; i < 4; ++i) whh[q * 4 + i] = *(const f32x4*)(rh + 256 * i);
    }
    asm volatile("" : "+v"(whh[0]), "+v"(whh[1]), "+v"(whh[2]), "+v"(whh[3]),
                      "+v"(whh[4]), "+v"(whh[5]), "+v"(whh[6]), "+v"(whh[7]),
                      "+v"(whh[8]), "+v"(whh[9]), "+v"(whh[10]), "+v"(whh[11]),
                      "+v"(whh[12]), "+v"(whh[13]), "+v"(whh[14]), "+v"(whh[15]));

    float c = c0[u];  // replicated across the wave
    f32x4 hr[4];
#pragma unroll
    for (int i = 0; i < 4; ++i) hr[i] = *(const f32x4*)(h0 + 4 * l + 256 * i);

    // gx pipeline: lane l holds element le=l&15 of gx[t] (q = le>>2, r = le&3)
    const float* gxb = gxT + (size_t)blockIdx.x * T_STEPS * 16;
    const int le = l & 15;
    float gxA = gxb[le];
    float gxB = gxb[16 + le];
    float gxC = 0.f;

    for (int t = 0; t < T_STEPS; ++t) {
        // gates = gx + whh . h_{t-1}
        float acc[4];
#pragma unroll
        for (int q = 0; q < 4; ++q) {
            float a = 0.f;
#pragma unroll
            for (int i = 0; i < 4; ++i) a += dot4(whh[q * 4 + i], hr[i]);
            acc[q] = a;
        }
#pragma unroll
        for (int m = 1; m < 64; m <<= 1) {
#pragma unroll
            for (int q = 0; q < 4; ++q) acc[q] += __shfl_xor(acc[q], m, 64);
        }
        const float gi = sigmoidf_(acc[0] + __shfl(gxA, 0 + w, 64));
        const float gf = sigmoidf_(acc[1] + __shfl(gxA, 4 + w, 64));
        const float gg = tanhf_   (acc[2] + __shfl(gxA, 8 + w, 64));
        const float go = sigmoidf_(acc[3] + __shfl(gxA, 12 + w, 64));
        c = gf * c + gi * gg;
        const float hval = go * tanhf_(c);   // identical on all 64 lanes

        if (l == 0) {
            // publish into THIS block's private line (R8 layout, byte-identical)
            const unsigned pk = ((unsigned)(t + 1) << 16) | bf16_rne(hval);
            unsigned int* slot = ring + (((t & 1) * NBLK + blockIdx.x) << 4) + w;
            asm volatile("global_store_dword %0, %1, off sc0 sc1"
                         :: "v"((unsigned long long)slot), "v"(pk) : "memory");
        }
        if (l == 1) out[(size_t)t * HDIM + u] = hval;   // off the publish path
        if (t == T_STEPS - 1) break;

        // prefetch gx[t+2]: one 64B L3-resident line, absorbed by poll's vmcnt
        {
            const int tn = (t + 2 < T_STEPS) ? (t + 2) : (T_STEPS - 1);
            gxC = gxb[(size_t)tn * 16 + le];
        }

        // wait for h_t: thread tid polls block tid's 16B line (its 4 units)
        {
            const unsigned e = (unsigned)(t + 1);
            const unsigned long long base =
                (unsigned long long)(ring + (((t & 1) * NBLK + tid) << 4));
            u32x4 p;
            for (;;) {
                asm volatile(
                    "global_load_dwordx4 %0, %1, off sc0 sc1\n\t"
                    "s_waitcnt vmcnt(0)"
                    : "=&v"(p)
                    : "v"(base)
                    : "memory");
                if ((p[0] >> 16) == e && (p[1] >> 16) == e &&
                    (p[2] >> 16) == e && (p[3] >> 16) == e) break;
            }
            const int ns = (t + 1) & 1;
            f32x4 hv;
            hv[0] = __uint_as_float(p[0] << 16);
            hv[1] = __uint_as_float(p[1] << 16);
            hv[2] = __uint_as_float(p[2] << 16);
            hv[3] = __uint_as_float(p[3] << 16);
            *(f32x4*)&h_lds[ns][4 * tid] = hv;   // units 4*tid .. 4*tid+3
        }
        __syncthreads();
        {
            const int ns = (t + 1) & 1;
#pragma unroll
            for (int i = 0; i < 4; ++i)
                hr[i] = *(const f32x4*)&h_lds[ns][4 * l + 256 * i];
        }
        gxA = gxB; gxB = gxC;
    }
}

extern "C" void kernel_launch(void* const* d_in, const int* in_sizes, int n_in,
                              void* d_out, int out_size, void* d_ws, size_t ws_size,
                              hipStream_t stream)
{
    const float* x    = (const float*)d_in[0];
    const float* W_ih = (const float*)d_in[1];
    const float* W_hh = (const float*)d_in[2];
    const float* b_ih = (const float*)d_in[3];
    const float* b_hh = (const float*)d_in[4];
    const float* h0   = (const float*)d_in[5];
    const float* c0   = (const float*)d_in[6];

    unsigned int* ring = (unsigned int*)d_ws;
    float* gxT = (float*)((char*)d_ws + (1u << 20));

    hipMemsetAsync(d_ws, 0, 2 * NBLK * 16 * sizeof(unsigned int), stream);
    gemm_gx<<<8192, 256, 0, stream>>>(x, W_ih, b_ih, b_hh, gxT);
    lstm_loop<<<NBLK, 256, 0, stream>>>(W_hh, h0, c0, gxT, (float*)d_out, ring);
}

// Round 10
// 25847.052 us; speedup vs baseline: 1.0916x; 1.0916x over previous
//
#include <hip/hip_runtime.h>
#include <cstdint>

#define T_STEPS 8192
#define HDIM    1024
#define NBLK    256
#define NTHR    256

typedef float        f32x4 __attribute__((ext_vector_type(4)));
typedef unsigned int u32x4 __attribute__((ext_vector_type(4)));

__device__ __forceinline__ float dot4(f32x4 a, f32x4 b) {
    return a[0] * b[0] + a[1] * b[1] + a[2] * b[2] + a[3] * b[3];
}
__device__ __forceinline__ float sigmoidf_(float v) { return 1.0f / (1.0f + __expf(-v)); }
__device__ __forceinline__ float tanhf_(float v)    { return 1.0f - 2.0f / (__expf(2.0f * v) + 1.0f); }
__device__ __forceinline__ unsigned bf16_rne(float f) {
    unsigned b = __float_as_uint(f);
    return (b + 0x7FFFu + ((b >> 16) & 1u)) >> 16;
}

// R8's fused structure + writer-private ring (fastest so far, 22.3ms).
// R10 changes ONLY the poll mechanics:
//  - wih pins dropped (R8 spilled pinned wih to scratch; stream from L2)
//  - poll load issued FIRST, before x-prefetch + gxp, so its ~700cy RT
//    overlaps with compute; check is then a near-free vmcnt(0)
//  - out[] store moved after detect (R8's first poll vmcnt(0) drained the
//    out store-ack + x HBM prefetch inside the detect path every step)
// Ring: u32[2][NBLK][16] — one writer CU per 64B line (R7 proved shared
// lines cost +50%). Payload (epoch16<<16)|bf16(h), validated R7/R8.
__global__ __launch_bounds__(NTHR, 1)
void lstm_persistent(const float* __restrict__ x,
                     const float* __restrict__ W_ih,
                     const float* __restrict__ W_hh,
                     const float* __restrict__ b_ih,
                     const float* __restrict__ b_hh,
                     const float* __restrict__ h0,
                     const float* __restrict__ c0,
                     float* __restrict__ out,
                     unsigned int* __restrict__ ring)
{
    __shared__ float h_lds[2][HDIM];

    const int tid = threadIdx.x;
    const int w   = tid >> 6;   // wave 0..3
    const int l   = tid & 63;   // lane
    const int u   = (blockIdx.x << 2) + w;

    // ---- weights: lane l covers elements 4l + 256i (+j) ----
    f32x4 whh[16], wih[16];
#pragma unroll
    for (int q = 0; q < 4; ++q) {
        const float* rh = W_hh + (size_t)(q * HDIM + u) * HDIM + 4 * l;
        const float* ri = W_ih + (size_t)(q * HDIM + u) * HDIM + 4 * l;
#pragma unroll
        for (int i = 0; i < 4; ++i) {
            whh[q * 4 + i] = *(const f32x4*)(rh + 256 * i);
            wih[q * 4 + i] = *(const f32x4*)(ri + 256 * i);
        }
    }
    // pin whh only (R9: pinning more than fits => scratch spills)
    asm volatile("" : "+v"(whh[0]), "+v"(whh[1]), "+v"(whh[2]), "+v"(whh[3]),
                      "+v"(whh[4]), "+v"(whh[5]), "+v"(whh[6]), "+v"(whh[7]),
                      "+v"(whh[8]), "+v"(whh[9]), "+v"(whh[10]), "+v"(whh[11]),
                      "+v"(whh[12]), "+v"(whh[13]), "+v"(whh[14]), "+v"(whh[15]));

    float bias[4];
#pragma unroll
    for (int q = 0; q < 4; ++q) bias[q] = b_ih[q * HDIM + u] + b_hh[q * HDIM + u];
    float c = c0[u];  // replicated across the wave

    f32x4 hr[4];
#pragma unroll
    for (int i = 0; i < 4; ++i) hr[i] = *(const f32x4*)(h0 + 4 * l + 256 * i);

    // x pipeline: gxp = Wih partials for step t; xr = x[t+1]; xn = x[t+2]
    float gxp[4];
    {
        f32x4 x0[4];
#pragma unroll
        for (int i = 0; i < 4; ++i) x0[i] = *(const f32x4*)(x + 4 * l + 256 * i);
#pragma unroll
        for (int q = 0; q < 4; ++q) {
            float a = 0.f;
#pragma unroll
            for (int i = 0; i < 4; ++i) a += dot4(wih[q * 4 + i], x0[i]);
            gxp[q] = a;
        }
    }
    f32x4 xr[4], xn[4];
#pragma unroll
    for (int i = 0; i < 4; ++i) xr[i] = *(const f32x4*)(x + HDIM + 4 * l + 256 * i);

    for (int t = 0; t < T_STEPS; ++t) {
        // gates = gxp + Whh . h_{t-1}
        float acc[4];
#pragma unroll
        for (int q = 0; q < 4; ++q) {
            float a = gxp[q];
#pragma unroll
            for (int i = 0; i < 4; ++i) a += dot4(whh[q * 4 + i], hr[i]);
            acc[q] = a;
        }
#pragma unroll
        for (int m = 1; m < 64; m <<= 1) {
#pragma unroll
            for (int q = 0; q < 4; ++q) acc[q] += __shfl_xor(acc[q], m, 64);
        }
        const float gi = sigmoidf_(acc[0] + bias[0]);
        const float gf = sigmoidf_(acc[1] + bias[1]);
        const float gg = tanhf_   (acc[2] + bias[2]);
        const float go = sigmoidf_(acc[3] + bias[3]);
        c = gf * c + gi * gg;
        const float hval = go * tanhf_(c);   // identical on all 64 lanes

        if (l == 0) {
            // publish FIRST — latency-critical
            const unsigned pk = ((unsigned)(t + 1) << 16) | bf16_rne(hval);
            unsigned int* slot = ring + (((t & 1) * NBLK + blockIdx.x) << 4) + w;
            asm volatile("global_store_dword %0, %1, off sc0 sc1"
                         :: "v"((unsigned long long)slot), "v"(pk) : "memory");
        }
        if (t == T_STEPS - 1) {
            if (l == 0) out[(size_t)t * HDIM + u] = hval;
            break;
        }

        const unsigned e = (unsigned)(t + 1);
        const unsigned long long base =
            (unsigned long long)(ring + (((t & 1) * NBLK + tid) << 4));

        // ---- issue poll load NOW (no wait) — RT overlaps with gxp below ----
        u32x4 p;
        asm volatile("global_load_dwordx4 %0, %1, off sc0 sc1"
                     : "=v"(p) : "v"(base) : "memory");

        // x[t+2] prefetch (younger than poll load; drained by gxp's own waits)
        {
            const int tn = (t + 2 < T_STEPS) ? (t + 2) : (T_STEPS - 1);
            const float* xp = x + (size_t)tn * HDIM;
#pragma unroll
            for (int i = 0; i < 4; ++i) xn[i] = *(const f32x4*)(xp + 4 * l + 256 * i);
        }
        // gx partials for step t+1 — consuming these loads drains the poll
        // load (older) progressively, so the check below is near-free
#pragma unroll
        for (int q = 0; q < 4; ++q) {
            float a = 0.f;
#pragma unroll
            for (int i = 0; i < 4; ++i) a += dot4(wih[q * 4 + i], xr[i]);
            gxp[q] = a;
        }

        // ---- check: tie p to the wait so uses can't hoist (rule #18) ----
        asm volatile("s_waitcnt vmcnt(0)" : "+v"(p) :: "memory");
        __builtin_amdgcn_sched_barrier(0);
        while (!((p[0] >> 16) == e && (p[1] >> 16) == e &&
                 (p[2] >> 16) == e && (p[3] >> 16) == e)) {
            asm volatile(
                "global_load_dwordx4 %0, %1, off sc0 sc1\n\t"
                "s_waitcnt vmcnt(0)"
                : "=&v"(p) : "v"(base) : "memory");
        }
        {
            const int ns = (t + 1) & 1;
            f32x4 hv;
            hv[0] = __uint_as_float(p[0] << 16);
            hv[1] = __uint_as_float(p[1] << 16);
            hv[2] = __uint_as_float(p[2] << 16);
            hv[3] = __uint_as_float(p[3] << 16);
            *(f32x4*)&h_lds[ns][4 * tid] = hv;   // units 4*tid .. 4*tid+3
        }
        // out store AFTER detect — its ack no longer sits in the poll drain
        if (l == 0) out[(size_t)t * HDIM + u] = hval;
        __syncthreads();
        {
            const int ns = (t + 1) & 1;
#pragma unroll
            for (int i = 0; i < 4; ++i)
                hr[i] = *(const f32x4*)&h_lds[ns][4 * l + 256 * i];
        }
#pragma unroll
        for (int i = 0; i < 4; ++i) xr[i] = xn[i];
    }
}

extern "C" void kernel_launch(void* const* d_in, const int* in_sizes, int n_in,
                              void* d_out, int out_size, void* d_ws, size_t ws_size,
                              hipStream_t stream)
{
    const float* x    = (const float*)d_in[0];
    const float* W_ih = (const float*)d_in[1];
    const float* W_hh = (const float*)d_in[2];
    const float* b_ih = (const float*)d_in[3];
    const float* b_hh = (const float*)d_in[4];
    const float* h0   = (const float*)d_in[5];
    const float* c0   = (const float*)d_in[6];

    unsigned int* ring = (unsigned int*)d_ws;
    hipMemsetAsync(d_ws, 0, 2 * NBLK * 16 * sizeof(unsigned int), stream);
    lstm_persistent<<<NBLK, NTHR, 0, stream>>>(x, W_ih, W_hh, b_ih, b_hh, h0, c0,
                                               (float*)d_out, ring);
}